// Round 1
// baseline (217.176 us; speedup 1.0000x reference)
//
#include <hip/hip_runtime.h>
#include <cstdint>
#include <cstddef>

// Problem constants (fixed by reference)
#define SLEN 2048
#define BSZ  2
#define EDIM 1024
#define NHEAD 16
#define DHEAD 64
#define PFW  16
#define NTOK (SLEN*BSZ)   // 4096

// GEMM tiling (m97-verified structure)
#define BM 128
#define BN 128
#define BK 32

typedef __attribute__((ext_vector_type(8))) short short8;   // 8 x bf16 bits
typedef __attribute__((ext_vector_type(4))) float floatx4;

__device__ __forceinline__ short f2bf(float f) {
  union { float f; uint32_t u; } v; v.f = f;
  uint32_t r = v.u + 0x7fffu + ((v.u >> 16) & 1u);   // round-nearest-even
  return (short)(r >> 16);
}
__device__ __forceinline__ float bf2f(short s) {
  union { uint32_t u; float f; } v; v.u = ((uint32_t)(uint16_t)s) << 16;
  return v.f;
}

// async global->LDS, 16B per lane; LDS dest = wave-uniform base + lane*16
__device__ __forceinline__ void async16(const void* g, void* l) {
  __builtin_amdgcn_global_load_lds((const __attribute__((address_space(1))) void*)g,
                                   (__attribute__((address_space(3))) void*)l,
                                   16, 0, 0);
}

// ---------------------------------------------------------------------------
// Weight transpose + fp32->bf16: Wt[n][k] = (bf16)W[k][n], 1024x1024, z in 0..3
// ---------------------------------------------------------------------------
__global__ __launch_bounds__(256) void transpose_kernel(
    const float* __restrict__ W0, const float* __restrict__ W1,
    const float* __restrict__ W2, const float* __restrict__ W3,
    short* __restrict__ Wt_base)
{
  const int z = blockIdx.z;
  const float* W = (z == 0) ? W0 : (z == 1) ? W1 : (z == 2) ? W2 : W3;
  short* Wt = Wt_base + (size_t)z * EDIM * EDIM;

  __shared__ float tile[32][33];
  const int tx = threadIdx.x & 31;
  const int ty = threadIdx.x >> 5;          // 0..7
  const int n0 = blockIdx.x * 32;
  const int k0 = blockIdx.y * 32;

#pragma unroll
  for (int i = 0; i < 4; ++i)
    tile[ty + i * 8][tx] = W[(size_t)(k0 + ty + i * 8) * EDIM + n0 + tx];
  __syncthreads();
#pragma unroll
  for (int i = 0; i < 4; ++i)
    Wt[(size_t)(n0 + ty + i * 8) * EDIM + k0 + tx] = f2bf(tile[tx][ty + i * 8]);
}

// ---------------------------------------------------------------------------
// LayerNorm: x (4096x1024 f32) -> xn (bf16). One block per row.
// ---------------------------------------------------------------------------
__global__ __launch_bounds__(256) void layernorm_kernel(
    const float* __restrict__ x, const float* __restrict__ g,
    const float* __restrict__ b, short* __restrict__ xn)
{
  const int row = blockIdx.x;
  const int tid = threadIdx.x;
  const float4 v = ((const float4*)(x + (size_t)row * EDIM))[tid];

  float s  = v.x + v.y + v.z + v.w;
  float ss = v.x * v.x + v.y * v.y + v.z * v.z + v.w * v.w;
#pragma unroll
  for (int off = 32; off; off >>= 1) {
    s  += __shfl_xor(s, off);
    ss += __shfl_xor(ss, off);
  }
  __shared__ float ws_s[4], ws_ss[4];
  const int lane = tid & 63, wave = tid >> 6;
  if (lane == 0) { ws_s[wave] = s; ws_ss[wave] = ss; }
  __syncthreads();
  s  = ws_s[0] + ws_s[1] + ws_s[2] + ws_s[3];
  ss = ws_ss[0] + ws_ss[1] + ws_ss[2] + ws_ss[3];

  const float mean = s * (1.0f / EDIM);
  const float var  = ss * (1.0f / EDIM) - mean * mean;
  const float rs   = rsqrtf(var + 1e-5f);

  const float4 gv = ((const float4*)g)[tid];
  const float4 bv = ((const float4*)b)[tid];
  short4 o;
  o.x = f2bf((v.x - mean) * rs * gv.x + bv.x);
  o.y = f2bf((v.y - mean) * rs * gv.y + bv.y);
  o.z = f2bf((v.z - mean) * rs * gv.z + bv.z);
  o.w = f2bf((v.w - mean) * rs * gv.w + bv.w);
  ((short4*)(xn + (size_t)row * EDIM))[tid] = o;
}

// ---------------------------------------------------------------------------
// GEMM mainloop: C[128x128] += A[bm:,k] * Bt[bn:,k]^T, bf16 MFMA 16x16x32.
// A: M x K row-major bf16. Bt: N x K row-major bf16. K multiple of 32.
// 256 threads = 4 waves, each wave 64x64 (4x4 of 16x16).
// ---------------------------------------------------------------------------
__device__ __forceinline__ void gemm_mainloop(
    const short* __restrict__ A, const short* __restrict__ Bt, int K,
    int bm, int bn, short* As, short* Bs, floatx4 (&acc)[4][4])
{
  const int tid  = threadIdx.x;
  const int lane = tid & 63;
  const int wave = tid >> 6;

  // staging: each wave fills 2 x 1KB chunks of As and Bs
  const int lrow = lane >> 2;          // 0..15
  const int lcol = (lane & 3) * 8;     // 0,8,16,24 (bf16 elems)
  const short* gA0 = A  + (size_t)(bm + wave * 32 + lrow) * K + lcol;
  const short* gA1 = gA0 + (size_t)16 * K;
  const short* gB0 = Bt + (size_t)(bn + wave * 32 + lrow) * K + lcol;
  const short* gB1 = gB0 + (size_t)16 * K;
  short* lA0 = As + wave * 1024;       // chunk base (shorts): c0*512 = wave*1024
  short* lA1 = lA0 + 512;
  short* lB0 = Bs + wave * 1024;
  short* lB1 = lB0 + 512;

  // fragment addressing
  const int wm = (wave >> 1) * 64;
  const int wn = (wave & 1) * 64;
  const int fr = lane & 15;            // row (A) / col-row (Bt)
  const int fq = (lane >> 4) * 8;      // k offset

  for (int k0 = 0; k0 < K; k0 += BK) {
    async16(gA0, lA0); async16(gA1, lA1);
    async16(gB0, lB0); async16(gB1, lB1);
    gA0 += BK; gA1 += BK; gB0 += BK; gB1 += BK;
    __syncthreads();   // compiler emits vmcnt(0) drain before barrier

    short8 af[4], bf[4];
#pragma unroll
    for (int mi = 0; mi < 4; ++mi)
      af[mi] = *(const short8*)(As + (size_t)(wm + mi * 16 + fr) * BK + fq);
#pragma unroll
    for (int ni = 0; ni < 4; ++ni)
      bf[ni] = *(const short8*)(Bs + (size_t)(wn + ni * 16 + fr) * BK + fq);
#pragma unroll
    for (int mi = 0; mi < 4; ++mi)
#pragma unroll
      for (int ni = 0; ni < 4; ++ni)
        acc[mi][ni] = __builtin_amdgcn_mfma_f32_16x16x32_bf16(
            af[mi], bf[ni], acc[mi][ni], 0, 0, 0);
    __syncthreads();
  }
}

// QKV projection: z selects (Wt, bias, out). Output bf16.
__global__ __launch_bounds__(256) void gemm_qkv(
    const short* __restrict__ xn, const short* __restrict__ Wt_base,
    const float* __restrict__ bq, const float* __restrict__ bk,
    const float* __restrict__ bv, short* __restrict__ qkv_base)
{
  __shared__ short As[BM * BK];
  __shared__ short Bs[BN * BK];
  const int z = blockIdx.z;
  const short* Bt   = Wt_base + (size_t)z * EDIM * EDIM;
  const float* bias = (z == 0) ? bq : (z == 1) ? bk : bv;
  short* out        = qkv_base + (size_t)z * NTOK * EDIM;

  const int bm = blockIdx.x * BM;
  const int bn = blockIdx.y * BN;
  floatx4 acc[4][4];
#pragma unroll
  for (int i = 0; i < 4; ++i)
#pragma unroll
    for (int j = 0; j < 4; ++j) { floatx4 zz = {0.f, 0.f, 0.f, 0.f}; acc[i][j] = zz; }

  gemm_mainloop(xn, Bt, EDIM, bm, bn, As, Bs, acc);

  const int lane = threadIdx.x & 63;
  const int wave = threadIdx.x >> 6;
  const int wm = (wave >> 1) * 64, wn = (wave & 1) * 64;
  const int r0 = bm + wm + ((lane >> 4) * 4);
  const int c0 = bn + wn + (lane & 15);
#pragma unroll
  for (int mi = 0; mi < 4; ++mi)
#pragma unroll
    for (int ni = 0; ni < 4; ++ni) {
      const floatx4 v = acc[mi][ni];
      const int col = c0 + ni * 16;
      const float bb = bias[col];
#pragma unroll
      for (int r = 0; r < 4; ++r) {
        const int row = r0 + mi * 16 + r;
        out[(size_t)row * EDIM + col] = f2bf(v[r] + bb);
      }
    }
}

// O projection + bias + residual: out f32.
__global__ __launch_bounds__(256) void gemm_o(
    const short* __restrict__ Aattn, const short* __restrict__ Wot,
    const float* __restrict__ bo, const float* __restrict__ residual,
    float* __restrict__ out)
{
  __shared__ short As[BM * BK];
  __shared__ short Bs[BN * BK];
  const int bm = blockIdx.x * BM;
  const int bn = blockIdx.y * BN;
  floatx4 acc[4][4];
#pragma unroll
  for (int i = 0; i < 4; ++i)
#pragma unroll
    for (int j = 0; j < 4; ++j) { floatx4 zz = {0.f, 0.f, 0.f, 0.f}; acc[i][j] = zz; }

  gemm_mainloop(Aattn, Wot, EDIM, bm, bn, As, Bs, acc);

  const int lane = threadIdx.x & 63;
  const int wave = threadIdx.x >> 6;
  const int wm = (wave >> 1) * 64, wn = (wave & 1) * 64;
  const int r0 = bm + wm + ((lane >> 4) * 4);
  const int c0 = bn + wn + (lane & 15);
#pragma unroll
  for (int mi = 0; mi < 4; ++mi)
#pragma unroll
    for (int ni = 0; ni < 4; ++ni) {
      const floatx4 v = acc[mi][ni];
      const int col = c0 + ni * 16;
      const float bb = bo[col];
#pragma unroll
      for (int r = 0; r < 4; ++r) {
        const int row = r0 + mi * 16 + r;
        const size_t idx = (size_t)row * EDIM + col;
        out[idx] = residual[idx] + v[r] + bb;
      }
    }
}

// ---------------------------------------------------------------------------
// Attention: one wave per (s,b,h). Window keys = rows (s-15+p) mod SL, p<16.
// ---------------------------------------------------------------------------
__global__ __launch_bounds__(256) void attn_kernel(
    const short* __restrict__ Q, const short* __restrict__ K,
    const short* __restrict__ V, short* __restrict__ O)
{
  const int gw   = blockIdx.x * 4 + (threadIdx.x >> 6);
  const int lane = threadIdx.x & 63;
  const int h = gw & (NHEAD - 1);
  const int b = (gw >> 4) & (BSZ - 1);
  const int s = gw >> 5;

  const int col = h * DHEAD + lane;
  const int tq  = s * BSZ + b;
  const float q = bf2f(Q[(size_t)tq * EDIM + col]);

  float scores[PFW], vv[PFW];
#pragma unroll
  for (int p = 0; p < PFW; ++p) {
    int sp = s - (PFW - 1) + p;
    if (sp < 0) sp += SLEN;
    const size_t idx = (size_t)(sp * BSZ + b) * EDIM + col;
    const float kk = bf2f(K[idx]);
    vv[p] = bf2f(V[idx]);
    float d = q * kk;
#pragma unroll
    for (int off = 32; off; off >>= 1) d += __shfl_xor(d, off);
    scores[p] = d * 0.125f;   // 1/sqrt(64)
  }

  float m = scores[0];
#pragma unroll
  for (int p = 1; p < PFW; ++p) m = fmaxf(m, scores[p]);
  float sum = 0.f;
#pragma unroll
  for (int p = 0; p < PFW; ++p) { scores[p] = __expf(scores[p] - m); sum += scores[p]; }
  const float inv = 1.0f / sum;

  float o = 0.f;
#pragma unroll
  for (int p = 0; p < PFW; ++p) o += scores[p] * vv[p];
  O[(size_t)tq * EDIM + col] = f2bf(o * inv);
}

// ---------------------------------------------------------------------------
extern "C" void kernel_launch(void* const* d_in, const int* in_sizes, int n_in,
                              void* d_out, int out_size, void* d_ws, size_t ws_size,
                              hipStream_t stream) {
  const float* x    = (const float*)d_in[0];
  const float* ln_g = (const float*)d_in[1];
  const float* ln_b = (const float*)d_in[2];
  const float* Wq   = (const float*)d_in[3];
  const float* bq   = (const float*)d_in[4];
  const float* Wk   = (const float*)d_in[5];
  const float* bk   = (const float*)d_in[6];
  const float* Wv   = (const float*)d_in[7];
  const float* bv   = (const float*)d_in[8];
  const float* Wo   = (const float*)d_in[9];
  const float* bo   = (const float*)d_in[10];
  float* out = (float*)d_out;

  char* ws = (char*)d_ws;
  short* xn   = (short*)(ws);                      // 8 MB: 4096x1024 bf16
  short* Wt   = (short*)(ws + ((size_t)8  << 20)); // 8 MB: 4 x 1024x1024 bf16 (q,k,v,o)
  short* QKV  = (short*)(ws + ((size_t)16 << 20)); // 24 MB: 3 x 4096x1024 bf16
  short* attn = (short*)(ws + ((size_t)40 << 20)); // 8 MB: 4096x1024 bf16

  transpose_kernel<<<dim3(32, 32, 4), 256, 0, stream>>>(Wq, Wk, Wv, Wo, Wt);
  layernorm_kernel<<<NTOK, 256, 0, stream>>>(x, ln_g, ln_b, xn);
  gemm_qkv<<<dim3(NTOK / BM, EDIM / BN, 3), 256, 0, stream>>>(xn, Wt, bq, bk, bv, QKV);
  attn_kernel<<<(SLEN * BSZ * NHEAD) / 4, 256, 0, stream>>>(
      QKV, QKV + (size_t)NTOK * EDIM, QKV + (size_t)2 * NTOK * EDIM, attn);
  gemm_o<<<dim3(NTOK / BM, EDIM / BN), 256, 0, stream>>>(
      attn, Wt + (size_t)3 * EDIM * EDIM, bo, x, out);
}

// Round 2
// 162.132 us; speedup vs baseline: 1.3395x; 1.3395x over previous
//
#include <hip/hip_runtime.h>
#include <cstdint>
#include <cstddef>

// Problem constants (fixed by reference)
#define SLEN 2048
#define BSZ  2
#define EDIM 1024
#define NHEAD 16
#define DHEAD 64
#define PFW  16
#define NTOK (SLEN*BSZ)   // 4096

// GEMM tiling (m97-verified structure)
#define BM 128
#define BN 128
#define BK 32

typedef __attribute__((ext_vector_type(8))) short short8;   // 8 x bf16 bits
typedef __attribute__((ext_vector_type(4))) float floatx4;

__device__ __forceinline__ short f2bf(float f) {
  union { float f; uint32_t u; } v; v.f = f;
  uint32_t r = v.u + 0x7fffu + ((v.u >> 16) & 1u);   // round-nearest-even
  return (short)(r >> 16);
}
__device__ __forceinline__ float bf2f(short s) {
  union { uint32_t u; float f; } v; v.u = ((uint32_t)(uint16_t)s) << 16;
  return v.f;
}

// async global->LDS, 16B per lane; LDS dest = wave-uniform base + lane*16
__device__ __forceinline__ void async16(const void* g, void* l) {
  __builtin_amdgcn_global_load_lds((const __attribute__((address_space(1))) void*)g,
                                   (__attribute__((address_space(3))) void*)l,
                                   16, 0, 0);
}

// ---------------------------------------------------------------------------
// Weight transpose + fp32->bf16: Wt[n][k] = (bf16)W[k][n], 1024x1024, z in 0..3
// ---------------------------------------------------------------------------
__global__ __launch_bounds__(256) void transpose_kernel(
    const float* __restrict__ W0, const float* __restrict__ W1,
    const float* __restrict__ W2, const float* __restrict__ W3,
    short* __restrict__ Wt_base)
{
  const int z = blockIdx.z;
  const float* W = (z == 0) ? W0 : (z == 1) ? W1 : (z == 2) ? W2 : W3;
  short* Wt = Wt_base + (size_t)z * EDIM * EDIM;

  __shared__ float tile[32][33];
  const int tx = threadIdx.x & 31;
  const int ty = threadIdx.x >> 5;          // 0..7
  const int n0 = blockIdx.x * 32;
  const int k0 = blockIdx.y * 32;

#pragma unroll
  for (int i = 0; i < 4; ++i)
    tile[ty + i * 8][tx] = W[(size_t)(k0 + ty + i * 8) * EDIM + n0 + tx];
  __syncthreads();
#pragma unroll
  for (int i = 0; i < 4; ++i)
    Wt[(size_t)(n0 + ty + i * 8) * EDIM + k0 + tx] = f2bf(tile[tx][ty + i * 8]);
}

// ---------------------------------------------------------------------------
// LayerNorm: x (4096x1024 f32) -> xn (bf16). One block per row.
// ---------------------------------------------------------------------------
__global__ __launch_bounds__(256) void layernorm_kernel(
    const float* __restrict__ x, const float* __restrict__ g,
    const float* __restrict__ b, short* __restrict__ xn)
{
  const int row = blockIdx.x;
  const int tid = threadIdx.x;
  const float4 v = ((const float4*)(x + (size_t)row * EDIM))[tid];

  float s  = v.x + v.y + v.z + v.w;
  float ss = v.x * v.x + v.y * v.y + v.z * v.z + v.w * v.w;
#pragma unroll
  for (int off = 32; off; off >>= 1) {
    s  += __shfl_xor(s, off);
    ss += __shfl_xor(ss, off);
  }
  __shared__ float ws_s[4], ws_ss[4];
  const int lane = tid & 63, wave = tid >> 6;
  if (lane == 0) { ws_s[wave] = s; ws_ss[wave] = ss; }
  __syncthreads();
  s  = ws_s[0] + ws_s[1] + ws_s[2] + ws_s[3];
  ss = ws_ss[0] + ws_ss[1] + ws_ss[2] + ws_ss[3];

  const float mean = s * (1.0f / EDIM);
  const float var  = ss * (1.0f / EDIM) - mean * mean;
  const float rs   = rsqrtf(var + 1e-5f);

  const float4 gv = ((const float4*)g)[tid];
  const float4 bv = ((const float4*)b)[tid];
  short4 o;
  o.x = f2bf((v.x - mean) * rs * gv.x + bv.x);
  o.y = f2bf((v.y - mean) * rs * gv.y + bv.y);
  o.z = f2bf((v.z - mean) * rs * gv.z + bv.z);
  o.w = f2bf((v.w - mean) * rs * gv.w + bv.w);
  ((short4*)(xn + (size_t)row * EDIM))[tid] = o;
}

// ---------------------------------------------------------------------------
// GEMM mainloop: C[128x128] += A[bm:,k] * Bt[bn:,k]^T, bf16 MFMA 16x16x32.
// ---------------------------------------------------------------------------
__device__ __forceinline__ void gemm_mainloop(
    const short* __restrict__ A, const short* __restrict__ Bt, int K,
    int bm, int bn, short* As, short* Bs, floatx4 (&acc)[4][4])
{
  const int tid  = threadIdx.x;
  const int lane = tid & 63;
  const int wave = tid >> 6;

  const int lrow = lane >> 2;          // 0..15
  const int lcol = (lane & 3) * 8;     // 0,8,16,24 (bf16 elems)
  const short* gA0 = A  + (size_t)(bm + wave * 32 + lrow) * K + lcol;
  const short* gA1 = gA0 + (size_t)16 * K;
  const short* gB0 = Bt + (size_t)(bn + wave * 32 + lrow) * K + lcol;
  const short* gB1 = gB0 + (size_t)16 * K;
  short* lA0 = As + wave * 1024;
  short* lA1 = lA0 + 512;
  short* lB0 = Bs + wave * 1024;
  short* lB1 = lB0 + 512;

  const int wm = (wave >> 1) * 64;
  const int wn = (wave & 1) * 64;
  const int fr = lane & 15;
  const int fq = (lane >> 4) * 8;

  for (int k0 = 0; k0 < K; k0 += BK) {
    async16(gA0, lA0); async16(gA1, lA1);
    async16(gB0, lB0); async16(gB1, lB1);
    gA0 += BK; gA1 += BK; gB0 += BK; gB1 += BK;
    __syncthreads();

    short8 af[4], bf[4];
#pragma unroll
    for (int mi = 0; mi < 4; ++mi)
      af[mi] = *(const short8*)(As + (size_t)(wm + mi * 16 + fr) * BK + fq);
#pragma unroll
    for (int ni = 0; ni < 4; ++ni)
      bf[ni] = *(const short8*)(Bs + (size_t)(wn + ni * 16 + fr) * BK + fq);
#pragma unroll
    for (int mi = 0; mi < 4; ++mi)
#pragma unroll
      for (int ni = 0; ni < 4; ++ni)
        acc[mi][ni] = __builtin_amdgcn_mfma_f32_16x16x32_bf16(
            af[mi], bf[ni], acc[mi][ni], 0, 0, 0);
    __syncthreads();
  }
}

// QKV projection: z selects (Wt, bias, out). Output bf16.
__global__ __launch_bounds__(256) void gemm_qkv(
    const short* __restrict__ xn, const short* __restrict__ Wt_base,
    const float* __restrict__ bq, const float* __restrict__ bk,
    const float* __restrict__ bv, short* __restrict__ qkv_base)
{
  __shared__ short As[BM * BK];
  __shared__ short Bs[BN * BK];
  const int z = blockIdx.z;
  const short* Bt   = Wt_base + (size_t)z * EDIM * EDIM;
  const float* bias = (z == 0) ? bq : (z == 1) ? bk : bv;
  short* out        = qkv_base + (size_t)z * NTOK * EDIM;

  const int bm = blockIdx.x * BM;
  const int bn = blockIdx.y * BN;
  floatx4 acc[4][4];
#pragma unroll
  for (int i = 0; i < 4; ++i)
#pragma unroll
    for (int j = 0; j < 4; ++j) { floatx4 zz = {0.f, 0.f, 0.f, 0.f}; acc[i][j] = zz; }

  gemm_mainloop(xn, Bt, EDIM, bm, bn, As, Bs, acc);

  const int lane = threadIdx.x & 63;
  const int wave = threadIdx.x >> 6;
  const int wm = (wave >> 1) * 64, wn = (wave & 1) * 64;
  const int r0 = bm + wm + ((lane >> 4) * 4);
  const int c0 = bn + wn + (lane & 15);
#pragma unroll
  for (int mi = 0; mi < 4; ++mi)
#pragma unroll
    for (int ni = 0; ni < 4; ++ni) {
      const floatx4 v = acc[mi][ni];
      const int col = c0 + ni * 16;
      const float bb = bias[col];
#pragma unroll
      for (int r = 0; r < 4; ++r) {
        const int row = r0 + mi * 16 + r;
        out[(size_t)row * EDIM + col] = f2bf(v[r] + bb);
      }
    }
}

// O projection + bias + residual: out f32.
__global__ __launch_bounds__(256) void gemm_o(
    const short* __restrict__ Aattn, const short* __restrict__ Wot,
    const float* __restrict__ bo, const float* __restrict__ residual,
    float* __restrict__ out)
{
  __shared__ short As[BM * BK];
  __shared__ short Bs[BN * BK];
  const int bm = blockIdx.x * BM;
  const int bn = blockIdx.y * BN;
  floatx4 acc[4][4];
#pragma unroll
  for (int i = 0; i < 4; ++i)
#pragma unroll
    for (int j = 0; j < 4; ++j) { floatx4 zz = {0.f, 0.f, 0.f, 0.f}; acc[i][j] = zz; }

  gemm_mainloop(Aattn, Wot, EDIM, bm, bn, As, Bs, acc);

  const int lane = threadIdx.x & 63;
  const int wave = threadIdx.x >> 6;
  const int wm = (wave >> 1) * 64, wn = (wave & 1) * 64;
  const int r0 = bm + wm + ((lane >> 4) * 4);
  const int c0 = bn + wn + (lane & 15);
#pragma unroll
  for (int mi = 0; mi < 4; ++mi)
#pragma unroll
    for (int ni = 0; ni < 4; ++ni) {
      const floatx4 v = acc[mi][ni];
      const int col = c0 + ni * 16;
      const float bb = bo[col];
#pragma unroll
      for (int r = 0; r < 4; ++r) {
        const int row = r0 + mi * 16 + r;
        const size_t idx = (size_t)row * EDIM + col;
        out[idx] = residual[idx] + v[r] + bb;
      }
    }
}

// ---------------------------------------------------------------------------
// MFMA attention. Block = 4 waves; wave w handles 16 queries s_blk+16w..+15
// for one (b,h). Keys per query: window [s-15, s] with mod-SLEN wrap.
// QK^T: A=Q (global short8 frags), B=K^T (global short8 frags, contiguous).
// Softmax: 16-lane butterfly (8 shfl total). P: LDS C->A layout round-trip.
// PV: V^T staged cooperatively in LDS (80-key shared window), 4 MFMAs.
// ---------------------------------------------------------------------------
#define VT_LD 80   // exactly 80 staged keys per block; byte stride 160 (16B-aligned)
#define PB_LD 40   // P row stride (shorts); byte stride 80 (16B-aligned)

__global__ __launch_bounds__(256) void attn_mfma(
    const short* __restrict__ Q, const short* __restrict__ K,
    const short* __restrict__ V, short* __restrict__ O)
{
  const int tid  = threadIdx.x;
  const int lane = tid & 63;
  const int wave = tid >> 6;
  const int quad = lane >> 4;         // 0..3
  const int l16  = lane & 15;

  const int bh = blockIdx.y;          // 0..31
  const int h  = bh & (NHEAD - 1);
  const int b  = bh >> 4;
  const int s_blk = blockIdx.x * 64;  // first query of block
  const int col0  = h * DHEAD;

  __shared__ __align__(16) short VT[64 * VT_LD];      // V^T: [dim][key offset]
  __shared__ __align__(16) short Pb[4][16 * PB_LD];   // per-wave P buffer

  // ---- cooperative V^T staging: keys s_blk-15 .. s_blk+64 (80 keys)
  for (int task = tid; task < 320; task += 256) {
    const int kp  = task >> 3;        // key pair 0..39
    const int dg  = task & 7;         // dim group 0..7
    const int kk0 = kp * 2;
    int sA = s_blk - 15 + kk0;
    int sB = sA + 1;
    if (sA < 0) sA += SLEN;  if (sA >= SLEN) sA -= SLEN;
    if (sB < 0) sB += SLEN;  if (sB >= SLEN) sB -= SLEN;
    const short8 vA = *(const short8*)(V + (size_t)(sA * BSZ + b) * EDIM + col0 + dg * 8);
    const short8 vB = *(const short8*)(V + (size_t)(sB * BSZ + b) * EDIM + col0 + dg * 8);
#pragma unroll
    for (int j = 0; j < 8; ++j) {
      const int d = dg * 8 + j;
      const uint32_t pack = (uint32_t)(uint16_t)vA[j] | ((uint32_t)(uint16_t)vB[j] << 16);
      *(uint32_t*)&VT[d * VT_LD + kk0] = pack;
    }
  }

  // ---- Q A-fragments (2 K-steps over 64 dims)
  const int sw = s_blk + wave * 16;   // wave's first query
  short8 aq[2];
  {
    const size_t base = (size_t)((sw + l16) * BSZ + b) * EDIM + col0 + quad * 8;
    aq[0] = *(const short8*)(Q + base);
    aq[1] = *(const short8*)(Q + base + 32);
  }
  // ---- K B-fragments: key tiles T=0 (sw-15..sw), T=1 (sw+1..sw+16)
  short8 bkf[2][2];
#pragma unroll
  for (int T = 0; T < 2; ++T) {
    int ks = sw - 15 + T * 16 + l16;
    if (ks < 0) ks += SLEN;
    if (ks >= SLEN) ks -= SLEN;
    const size_t base = (size_t)(ks * BSZ + b) * EDIM + col0 + quad * 8;
    bkf[T][0] = *(const short8*)(K + base);
    bkf[T][1] = *(const short8*)(K + base + 32);
  }

  // ---- scores: S[T] is 16 queries x 16 keys (C-layout: col=l16, row=quad*4+r)
  floatx4 S[2];
  { floatx4 zz = {0.f, 0.f, 0.f, 0.f}; S[0] = zz; S[1] = zz; }
#pragma unroll
  for (int T = 0; T < 2; ++T) {
    S[T] = __builtin_amdgcn_mfma_f32_16x16x32_bf16(aq[0], bkf[T][0], S[T], 0, 0, 0);
    S[T] = __builtin_amdgcn_mfma_f32_16x16x32_bf16(aq[1], bkf[T][1], S[T], 0, 0, 0);
  }

  // ---- band mask + softmax (row = query, cols 0..31 of the 32-key window)
  float sc[2][4];
#pragma unroll
  for (int T = 0; T < 2; ++T)
#pragma unroll
    for (int r = 0; r < 4; ++r) {
      const int m = quad * 4 + r;
      const int c = T * 16 + l16;
      const int d = c - m;                 // valid iff 0 <= d <= 15
      sc[T][r] = (d >= 0 && d <= 15) ? S[T][r] * 0.125f : -1e30f;
    }
  float mx[4], sm[4];
#pragma unroll
  for (int r = 0; r < 4; ++r) mx[r] = fmaxf(sc[0][r], sc[1][r]);
#pragma unroll
  for (int off = 1; off <= 8; off <<= 1)
#pragma unroll
    for (int r = 0; r < 4; ++r) mx[r] = fmaxf(mx[r], __shfl_xor(mx[r], off));
  float p[2][4];
#pragma unroll
  for (int r = 0; r < 4; ++r) {
    p[0][r] = __expf(sc[0][r] - mx[r]);
    p[1][r] = __expf(sc[1][r] - mx[r]);
    sm[r] = p[0][r] + p[1][r];
  }
#pragma unroll
  for (int off = 1; off <= 8; off <<= 1)
#pragma unroll
    for (int r = 0; r < 4; ++r) sm[r] += __shfl_xor(sm[r], off);

  __syncthreads();   // VT staging complete (also orders Pb writes below)

  // ---- P: C-layout -> A-layout via LDS (bf16)
  short* Pw = Pb[wave];
#pragma unroll
  for (int T = 0; T < 2; ++T)
#pragma unroll
    for (int r = 0; r < 4; ++r) {
      const int m = quad * 4 + r;
      const int c = T * 16 + l16;
      Pw[m * PB_LD + c] = f2bf(p[T][r]);
    }
  __syncthreads();
  const short8 ap = *(const short8*)(Pw + l16 * PB_LD + quad * 8);

  // ---- PV: B-frags from VT (keys 16*wave + quad*8.. , dims nt*16 + l16)
  floatx4 Oacc[4];
  { floatx4 zz = {0.f, 0.f, 0.f, 0.f}; Oacc[0] = zz; Oacc[1] = zz; Oacc[2] = zz; Oacc[3] = zz; }
#pragma unroll
  for (int nt = 0; nt < 4; ++nt) {
    const short8 bv = *(const short8*)(VT + (nt * 16 + l16) * VT_LD + wave * 16 + quad * 8);
    Oacc[nt] = __builtin_amdgcn_mfma_f32_16x16x32_bf16(ap, bv, Oacc[nt], 0, 0, 0);
  }

  // ---- store (divide by row sums; C-layout rows match sm[r] rows)
#pragma unroll
  for (int nt = 0; nt < 4; ++nt)
#pragma unroll
    for (int r = 0; r < 4; ++r) {
      const int m = quad * 4 + r;
      const size_t idx = (size_t)((sw + m) * BSZ + b) * EDIM + col0 + nt * 16 + l16;
      O[idx] = f2bf(Oacc[nt][r] / sm[r]);
    }
}

// ---------------------------------------------------------------------------
extern "C" void kernel_launch(void* const* d_in, const int* in_sizes, int n_in,
                              void* d_out, int out_size, void* d_ws, size_t ws_size,
                              hipStream_t stream) {
  const float* x    = (const float*)d_in[0];
  const float* ln_g = (const float*)d_in[1];
  const float* ln_b = (const float*)d_in[2];
  const float* Wq   = (const float*)d_in[3];
  const float* bq   = (const float*)d_in[4];
  const float* Wk   = (const float*)d_in[5];
  const float* bk   = (const float*)d_in[6];
  const float* Wv   = (const float*)d_in[7];
  const float* bv   = (const float*)d_in[8];
  const float* Wo   = (const float*)d_in[9];
  const float* bo   = (const float*)d_in[10];
  float* out = (float*)d_out;

  char* ws = (char*)d_ws;
  short* xn   = (short*)(ws);                      // 8 MB
  short* Wt   = (short*)(ws + ((size_t)8  << 20)); // 8 MB: Wq^T,Wk^T,Wv^T,Wo^T bf16
  short* QKV  = (short*)(ws + ((size_t)16 << 20)); // 24 MB
  short* attn = (short*)(ws + ((size_t)40 << 20)); // 8 MB

  transpose_kernel<<<dim3(32, 32, 4), 256, 0, stream>>>(Wq, Wk, Wv, Wo, Wt);
  layernorm_kernel<<<NTOK, 256, 0, stream>>>(x, ln_g, ln_b, xn);
  gemm_qkv<<<dim3(NTOK / BM, EDIM / BN, 3), 256, 0, stream>>>(xn, Wt, bq, bk, bv, QKV);
  attn_mfma<<<dim3(SLEN / 64, BSZ * NHEAD), 256, 0, stream>>>(
      QKV, QKV + (size_t)NTOK * EDIM, QKV + (size_t)2 * NTOK * EDIM, attn);
  gemm_o<<<dim3(NTOK / BM, EDIM / BN), 256, 0, stream>>>(
      attn, Wt + (size_t)3 * EDIM * EDIM, bo, x, out);
}

// Round 3
// 159.639 us; speedup vs baseline: 1.3604x; 1.0156x over previous
//
#include <hip/hip_runtime.h>
#include <cstdint>
#include <cstddef>

// Problem constants (fixed by reference)
#define SLEN 2048
#define BSZ  2
#define EDIM 1024
#define NHEAD 16
#define DHEAD 64
#define PFW  16
#define NTOK (SLEN*BSZ)   // 4096

// GEMM tiling (m97-verified structure)
#define BK 32

typedef __attribute__((ext_vector_type(8))) short short8;   // 8 x bf16 bits
typedef __attribute__((ext_vector_type(4))) float floatx4;

__device__ __forceinline__ short f2bf(float f) {
  union { float f; uint32_t u; } v; v.f = f;
  uint32_t r = v.u + 0x7fffu + ((v.u >> 16) & 1u);   // round-nearest-even
  return (short)(r >> 16);
}
__device__ __forceinline__ float bf2f(short s) {
  union { uint32_t u; float f; } v; v.u = ((uint32_t)(uint16_t)s) << 16;
  return v.f;
}

// async global->LDS, 16B per lane; LDS dest = wave-uniform base + lane*16
__device__ __forceinline__ void async16(const void* g, void* l) {
  __builtin_amdgcn_global_load_lds((const __attribute__((address_space(1))) void*)g,
                                   (__attribute__((address_space(3))) void*)l,
                                   16, 0, 0);
}

// ---------------------------------------------------------------------------
// prep: blocks [0,NTOK) do LayerNorm rows; blocks [NTOK, NTOK+4096) do
// weight transpose tiles (z = tile>>10 selects Wq/Wk/Wv/Wo).
// ---------------------------------------------------------------------------
__global__ __launch_bounds__(256) void prep_kernel(
    const float* __restrict__ x, const float* __restrict__ g,
    const float* __restrict__ b, short* __restrict__ xn,
    const float* __restrict__ W0, const float* __restrict__ W1,
    const float* __restrict__ W2, const float* __restrict__ W3,
    short* __restrict__ Wt_base)
{
  const int bid = blockIdx.x;
  const int tid = threadIdx.x;

  if (bid < NTOK) {
    // ---- LayerNorm row
    const int row = bid;
    const float4 v = ((const float4*)(x + (size_t)row * EDIM))[tid];
    float s  = v.x + v.y + v.z + v.w;
    float ss = v.x * v.x + v.y * v.y + v.z * v.z + v.w * v.w;
#pragma unroll
    for (int off = 32; off; off >>= 1) {
      s  += __shfl_xor(s, off);
      ss += __shfl_xor(ss, off);
    }
    __shared__ float ws_s[4], ws_ss[4];
    const int lane = tid & 63, wave = tid >> 6;
    if (lane == 0) { ws_s[wave] = s; ws_ss[wave] = ss; }
    __syncthreads();
    s  = ws_s[0] + ws_s[1] + ws_s[2] + ws_s[3];
    ss = ws_ss[0] + ws_ss[1] + ws_ss[2] + ws_ss[3];

    const float mean = s * (1.0f / EDIM);
    const float var  = ss * (1.0f / EDIM) - mean * mean;
    const float rs   = rsqrtf(var + 1e-5f);

    const float4 gv = ((const float4*)g)[tid];
    const float4 bv = ((const float4*)b)[tid];
    short4 o;
    o.x = f2bf((v.x - mean) * rs * gv.x + bv.x);
    o.y = f2bf((v.y - mean) * rs * gv.y + bv.y);
    o.z = f2bf((v.z - mean) * rs * gv.z + bv.z);
    o.w = f2bf((v.w - mean) * rs * gv.w + bv.w);
    ((short4*)(xn + (size_t)row * EDIM))[tid] = o;
  } else {
    // ---- weight transpose tile: Wt[n][k] = (bf16)W[k][n]
    const int t = bid - NTOK;
    const int z = t >> 10;
    const int rem = t & 1023;
    const int n0 = (rem & 31) * 32;
    const int k0 = (rem >> 5) * 32;
    const float* W = (z == 0) ? W0 : (z == 1) ? W1 : (z == 2) ? W2 : W3;
    short* Wt = Wt_base + (size_t)z * EDIM * EDIM;

    __shared__ float tile[32][33];
    const int tx = tid & 31;
    const int ty = tid >> 5;          // 0..7
#pragma unroll
    for (int i = 0; i < 4; ++i)
      tile[ty + i * 8][tx] = W[(size_t)(k0 + ty + i * 8) * EDIM + n0 + tx];
    __syncthreads();
#pragma unroll
    for (int i = 0; i < 4; ++i)
      Wt[(size_t)(n0 + ty + i * 8) * EDIM + k0 + tx] = f2bf(tile[tx][ty + i * 8]);
  }
}

// ---------------------------------------------------------------------------
// QKV projection: 128x128 tile (m97 structure), z selects (Wt, bias, out).
// ---------------------------------------------------------------------------
__global__ __launch_bounds__(256) void gemm_qkv(
    const short* __restrict__ xn, const short* __restrict__ Wt_base,
    const float* __restrict__ bq, const float* __restrict__ bk,
    const float* __restrict__ bv, short* __restrict__ qkv_base)
{
  __shared__ short As[128 * BK];
  __shared__ short Bs[128 * BK];
  const int z = blockIdx.z;
  const short* Bt   = Wt_base + (size_t)z * EDIM * EDIM;
  const float* bias = (z == 0) ? bq : (z == 1) ? bk : bv;
  short* out        = qkv_base + (size_t)z * NTOK * EDIM;

  const int bm = blockIdx.x * 128;
  const int bn = blockIdx.y * 128;
  const int tid  = threadIdx.x;
  const int lane = tid & 63;
  const int wave = tid >> 6;

  floatx4 acc[4][4];
#pragma unroll
  for (int i = 0; i < 4; ++i)
#pragma unroll
    for (int j = 0; j < 4; ++j) { floatx4 zz = {0.f, 0.f, 0.f, 0.f}; acc[i][j] = zz; }

  const int lrow = lane >> 2;          // 0..15
  const int lcol = (lane & 3) * 8;     // 0,8,16,24
  const short* gA0 = xn + (size_t)(bm + wave * 32 + lrow) * EDIM + lcol;
  const short* gA1 = gA0 + (size_t)16 * EDIM;
  const short* gB0 = Bt + (size_t)(bn + wave * 32 + lrow) * EDIM + lcol;
  const short* gB1 = gB0 + (size_t)16 * EDIM;
  short* lA0 = As + wave * 1024;
  short* lA1 = lA0 + 512;
  short* lB0 = Bs + wave * 1024;
  short* lB1 = lB0 + 512;

  const int wm = (wave >> 1) * 64;
  const int wn = (wave & 1) * 64;
  const int fr = lane & 15;
  const int fq = (lane >> 4) * 8;

  for (int k0 = 0; k0 < EDIM; k0 += BK) {
    async16(gA0, lA0); async16(gA1, lA1);
    async16(gB0, lB0); async16(gB1, lB1);
    gA0 += BK; gA1 += BK; gB0 += BK; gB1 += BK;
    __syncthreads();

    short8 af[4], bf[4];
#pragma unroll
    for (int mi = 0; mi < 4; ++mi)
      af[mi] = *(const short8*)(As + (size_t)(wm + mi * 16 + fr) * BK + fq);
#pragma unroll
    for (int ni = 0; ni < 4; ++ni)
      bf[ni] = *(const short8*)(Bs + (size_t)(wn + ni * 16 + fr) * BK + fq);
#pragma unroll
    for (int mi = 0; mi < 4; ++mi)
#pragma unroll
      for (int ni = 0; ni < 4; ++ni)
        acc[mi][ni] = __builtin_amdgcn_mfma_f32_16x16x32_bf16(
            af[mi], bf[ni], acc[mi][ni], 0, 0, 0);
    __syncthreads();
  }

  const int r0 = bm + wm + ((lane >> 4) * 4);
  const int c0 = bn + wn + (lane & 15);
#pragma unroll
  for (int mi = 0; mi < 4; ++mi)
#pragma unroll
    for (int ni = 0; ni < 4; ++ni) {
      const floatx4 v = acc[mi][ni];
      const int col = c0 + ni * 16;
      const float bb = bias[col];
#pragma unroll
      for (int r = 0; r < 4; ++r) {
        const int row = r0 + mi * 16 + r;
        out[(size_t)row * EDIM + col] = f2bf(v[r] + bb);
      }
    }
}

// ---------------------------------------------------------------------------
// O projection + bias + residual. 64x128 tile: grid 64x8=512 blocks =
// 2 blocks/CU (vs 1 at 128x128) -> 8 waves/CU latency hiding.
// ---------------------------------------------------------------------------
__global__ __launch_bounds__(256) void gemm_o(
    const short* __restrict__ Aattn, const short* __restrict__ Wot,
    const float* __restrict__ bo, const float* __restrict__ residual,
    float* __restrict__ out)
{
  __shared__ short As[64 * BK];    // 4 KB
  __shared__ short Bs[128 * BK];   // 8 KB
  const int bm = blockIdx.x * 64;
  const int bn = blockIdx.y * 128;
  const int tid  = threadIdx.x;
  const int lane = tid & 63;
  const int wave = tid >> 6;

  floatx4 acc[2][4];
#pragma unroll
  for (int i = 0; i < 2; ++i)
#pragma unroll
    for (int j = 0; j < 4; ++j) { floatx4 zz = {0.f, 0.f, 0.f, 0.f}; acc[i][j] = zz; }

  const int lrow = lane >> 2;
  const int lcol = (lane & 3) * 8;
  // A: 4 chunks of 16 rows; wave stages chunk `wave` (rows wave*16..+15)
  const short* gA0 = Aattn + (size_t)(bm + wave * 16 + lrow) * EDIM + lcol;
  // B: 8 chunks; wave stages chunks 2w, 2w+1 (rows wave*32..+31)
  const short* gB0 = Wot + (size_t)(bn + wave * 32 + lrow) * EDIM + lcol;
  const short* gB1 = gB0 + (size_t)16 * EDIM;
  short* lA0 = As + wave * 512;
  short* lB0 = Bs + wave * 1024;
  short* lB1 = lB0 + 512;

  const int wm = (wave >> 1) * 32;   // 0 or 32
  const int wn = (wave & 1) * 64;    // 0 or 64
  const int fr = lane & 15;
  const int fq = (lane >> 4) * 8;

  for (int k0 = 0; k0 < EDIM; k0 += BK) {
    async16(gA0, lA0);
    async16(gB0, lB0); async16(gB1, lB1);
    gA0 += BK; gB0 += BK; gB1 += BK;
    __syncthreads();

    short8 af[2], bf[4];
#pragma unroll
    for (int mi = 0; mi < 2; ++mi)
      af[mi] = *(const short8*)(As + (size_t)(wm + mi * 16 + fr) * BK + fq);
#pragma unroll
    for (int ni = 0; ni < 4; ++ni)
      bf[ni] = *(const short8*)(Bs + (size_t)(wn + ni * 16 + fr) * BK + fq);
#pragma unroll
    for (int mi = 0; mi < 2; ++mi)
#pragma unroll
      for (int ni = 0; ni < 4; ++ni)
        acc[mi][ni] = __builtin_amdgcn_mfma_f32_16x16x32_bf16(
            af[mi], bf[ni], acc[mi][ni], 0, 0, 0);
    __syncthreads();
  }

  const int r0 = bm + wm + ((lane >> 4) * 4);
  const int c0 = bn + wn + (lane & 15);
#pragma unroll
  for (int mi = 0; mi < 2; ++mi)
#pragma unroll
    for (int ni = 0; ni < 4; ++ni) {
      const floatx4 v = acc[mi][ni];
      const int col = c0 + ni * 16;
      const float bb = bo[col];
#pragma unroll
      for (int r = 0; r < 4; ++r) {
        const int row = r0 + mi * 16 + r;
        const size_t idx = (size_t)row * EDIM + col;
        out[idx] = residual[idx] + v[r] + bb;
      }
    }
}

// ---------------------------------------------------------------------------
// MFMA attention. Block = 4 waves; wave w handles 16 queries s_blk+16w..+15
// for one (b,h). Keys per query: window [s-15, s] with mod-SLEN wrap.
// ---------------------------------------------------------------------------
#define VT_LD 80   // 80 staged keys per block; byte stride 160 (16B-aligned)
#define PB_LD 40   // P row stride (shorts); byte stride 80 (16B-aligned)

__global__ __launch_bounds__(256) void attn_mfma(
    const short* __restrict__ Q, const short* __restrict__ K,
    const short* __restrict__ V, short* __restrict__ O)
{
  const int tid  = threadIdx.x;
  const int lane = tid & 63;
  const int wave = tid >> 6;
  const int quad = lane >> 4;         // 0..3
  const int l16  = lane & 15;

  const int bh = blockIdx.y;          // 0..31
  const int h  = bh & (NHEAD - 1);
  const int b  = bh >> 4;
  const int s_blk = blockIdx.x * 64;  // first query of block
  const int col0  = h * DHEAD;

  __shared__ __align__(16) short VT[64 * VT_LD];      // V^T: [dim][key offset]
  __shared__ __align__(16) short Pb[4][16 * PB_LD];   // per-wave P buffer

  // ---- cooperative V^T staging: keys s_blk-15 .. s_blk+64 (80 keys)
  for (int task = tid; task < 320; task += 256) {
    const int kp  = task >> 3;        // key pair 0..39
    const int dg  = task & 7;         // dim group 0..7
    const int kk0 = kp * 2;
    int sA = s_blk - 15 + kk0;
    int sB = sA + 1;
    if (sA < 0) sA += SLEN;  if (sA >= SLEN) sA -= SLEN;
    if (sB < 0) sB += SLEN;  if (sB >= SLEN) sB -= SLEN;
    const short8 vA = *(const short8*)(V + (size_t)(sA * BSZ + b) * EDIM + col0 + dg * 8);
    const short8 vB = *(const short8*)(V + (size_t)(sB * BSZ + b) * EDIM + col0 + dg * 8);
#pragma unroll
    for (int j = 0; j < 8; ++j) {
      const int d = dg * 8 + j;
      const uint32_t pack = (uint32_t)(uint16_t)vA[j] | ((uint32_t)(uint16_t)vB[j] << 16);
      *(uint32_t*)&VT[d * VT_LD + kk0] = pack;
    }
  }

  // ---- Q A-fragments (2 K-steps over 64 dims)
  const int sw = s_blk + wave * 16;   // wave's first query
  short8 aq[2];
  {
    const size_t base = (size_t)((sw + l16) * BSZ + b) * EDIM + col0 + quad * 8;
    aq[0] = *(const short8*)(Q + base);
    aq[1] = *(const short8*)(Q + base + 32);
  }
  // ---- K B-fragments: key tiles T=0 (sw-15..sw), T=1 (sw+1..sw+16)
  short8 bkf[2][2];
#pragma unroll
  for (int T = 0; T < 2; ++T) {
    int ks = sw - 15 + T * 16 + l16;
    if (ks < 0) ks += SLEN;
    if (ks >= SLEN) ks -= SLEN;
    const size_t base = (size_t)(ks * BSZ + b) * EDIM + col0 + quad * 8;
    bkf[T][0] = *(const short8*)(K + base);
    bkf[T][1] = *(const short8*)(K + base + 32);
  }

  // ---- scores: S[T] is 16 queries x 16 keys (C-layout: col=l16, row=quad*4+r)
  floatx4 S[2];
  { floatx4 zz = {0.f, 0.f, 0.f, 0.f}; S[0] = zz; S[1] = zz; }
#pragma unroll
  for (int T = 0; T < 2; ++T) {
    S[T] = __builtin_amdgcn_mfma_f32_16x16x32_bf16(aq[0], bkf[T][0], S[T], 0, 0, 0);
    S[T] = __builtin_amdgcn_mfma_f32_16x16x32_bf16(aq[1], bkf[T][1], S[T], 0, 0, 0);
  }

  // ---- band mask + softmax
  float sc[2][4];
#pragma unroll
  for (int T = 0; T < 2; ++T)
#pragma unroll
    for (int r = 0; r < 4; ++r) {
      const int m = quad * 4 + r;
      const int c = T * 16 + l16;
      const int d = c - m;                 // valid iff 0 <= d <= 15
      sc[T][r] = (d >= 0 && d <= 15) ? S[T][r] * 0.125f : -1e30f;
    }
  float mx[4], sm[4];
#pragma unroll
  for (int r = 0; r < 4; ++r) mx[r] = fmaxf(sc[0][r], sc[1][r]);
#pragma unroll
  for (int off = 1; off <= 8; off <<= 1)
#pragma unroll
    for (int r = 0; r < 4; ++r) mx[r] = fmaxf(mx[r], __shfl_xor(mx[r], off));
  float p[2][4];
#pragma unroll
  for (int r = 0; r < 4; ++r) {
    p[0][r] = __expf(sc[0][r] - mx[r]);
    p[1][r] = __expf(sc[1][r] - mx[r]);
    sm[r] = p[0][r] + p[1][r];
  }
#pragma unroll
  for (int off = 1; off <= 8; off <<= 1)
#pragma unroll
    for (int r = 0; r < 4; ++r) sm[r] += __shfl_xor(sm[r], off);

  __syncthreads();   // VT staging complete (also orders Pb writes below)

  // ---- P: C-layout -> A-layout via LDS (bf16)
  short* Pw = Pb[wave];
#pragma unroll
  for (int T = 0; T < 2; ++T)
#pragma unroll
    for (int r = 0; r < 4; ++r) {
      const int m = quad * 4 + r;
      const int c = T * 16 + l16;
      Pw[m * PB_LD + c] = f2bf(p[T][r]);
    }
  __syncthreads();
  const short8 ap = *(const short8*)(Pw + l16 * PB_LD + quad * 8);

  // ---- PV: B-frags from VT
  floatx4 Oacc[4];
  { floatx4 zz = {0.f, 0.f, 0.f, 0.f}; Oacc[0] = zz; Oacc[1] = zz; Oacc[2] = zz; Oacc[3] = zz; }
#pragma unroll
  for (int nt = 0; nt < 4; ++nt) {
    const short8 bv = *(const short8*)(VT + (nt * 16 + l16) * VT_LD + wave * 16 + quad * 8);
    Oacc[nt] = __builtin_amdgcn_mfma_f32_16x16x32_bf16(ap, bv, Oacc[nt], 0, 0, 0);
  }

  // ---- store (divide by row sums)
#pragma unroll
  for (int nt = 0; nt < 4; ++nt)
#pragma unroll
    for (int r = 0; r < 4; ++r) {
      const int m = quad * 4 + r;
      const size_t idx = (size_t)((sw + m) * BSZ + b) * EDIM + col0 + nt * 16 + l16;
      O[idx] = f2bf(Oacc[nt][r] / sm[r]);
    }
}

// ---------------------------------------------------------------------------
extern "C" void kernel_launch(void* const* d_in, const int* in_sizes, int n_in,
                              void* d_out, int out_size, void* d_ws, size_t ws_size,
                              hipStream_t stream) {
  const float* x    = (const float*)d_in[0];
  const float* ln_g = (const float*)d_in[1];
  const float* ln_b = (const float*)d_in[2];
  const float* Wq   = (const float*)d_in[3];
  const float* bq   = (const float*)d_in[4];
  const float* Wk   = (const float*)d_in[5];
  const float* bk   = (const float*)d_in[6];
  const float* Wv   = (const float*)d_in[7];
  const float* bv   = (const float*)d_in[8];
  const float* Wo   = (const float*)d_in[9];
  const float* bo   = (const float*)d_in[10];
  float* out = (float*)d_out;

  char* ws = (char*)d_ws;
  short* xn   = (short*)(ws);                      // 8 MB
  short* Wt   = (short*)(ws + ((size_t)8  << 20)); // 8 MB: Wq^T,Wk^T,Wv^T,Wo^T bf16
  short* QKV  = (short*)(ws + ((size_t)16 << 20)); // 24 MB
  short* attn = (short*)(ws + ((size_t)40 << 20)); // 8 MB

  prep_kernel<<<NTOK + 4096, 256, 0, stream>>>(x, ln_g, ln_b, xn, Wq, Wk, Wv, Wo, Wt);
  gemm_qkv<<<dim3(NTOK / 128, EDIM / 128, 3), 256, 0, stream>>>(xn, Wt, bq, bk, bv, QKV);
  attn_mfma<<<dim3(SLEN / 64, BSZ * NHEAD), 256, 0, stream>>>(
      QKV, QKV + (size_t)NTOK * EDIM, QKV + (size_t)2 * NTOK * EDIM, attn);
  gemm_o<<<dim3(NTOK / 64, EDIM / 128), 256, 0, stream>>>(
      attn, Wt + (size_t)3 * EDIM * EDIM, bo, x, out);
}